// Round 6
// baseline (518.454 us; speedup 1.0000x reference)
//
#include <hip/hip_runtime.h>
#include <hip/hip_bf16.h>
#include <stdint.h>

// Problem constants
#define BB   8192   // batch
#define DD   8      // features
#define PP   10     // poly basis width
#define RR   512    // TT rank
#define OUTD 64     // output dim
#define KK   5120   // expanded K = PP*RR (j-major: kk = j*512 + i)

typedef __bf16 bf16x8 __attribute__((ext_vector_type(8)));
typedef float  f32x4  __attribute__((ext_vector_type(4)));

__device__ __forceinline__ void gload_lds16(const __hip_bfloat16* g, __hip_bfloat16* l) {
    __builtin_amdgcn_global_load_lds(
        (const __attribute__((address_space(1))) void*)g,
        (__attribute__((address_space(3))) void*)l, 16, 0, 0);
}

// ---------------------------------------------------------------------------
// Prep: tanh + pack G_mid[c][i][j][n] into MFMA-fragment-linear layout:
//   tBf[c][j][kc][nt][lane][e]  (each 16x16x32 B-fragment = contiguous 1KB)
//   fragment elem: n = nt*16 + (lane&15), i = kc*32 + (lane>>4)*8 + e
// grid (16,10,6) = (kc, j, c), 256 threads; each thread packs 8 chunks of 16B.
// ---------------------------------------------------------------------------
__global__ __launch_bounds__(256) void frag_pack_mid(
        const float* __restrict__ G, __hip_bfloat16* __restrict__ tBf) {
    const int kc = blockIdx.x, j = blockIdx.y, c = blockIdx.z;
    const float* Gc = G + (size_t)c * (RR * PP * RR);
    __hip_bfloat16* dst = tBf + (size_t)c * (RR * KK)
                        + ((size_t)(j * 16 + kc) * 32) * 512;
    #pragma unroll
    for (int cc = 0; cc < 8; ++cc) {
        const int ch = cc * 256 + threadIdx.x;      // 0..2047
        const int nt = ch >> 6, l = ch & 63;
        const int n  = nt * 16 + (l & 15);
        const int i0 = kc * 32 + ((l >> 4) << 3);
        union { __hip_bfloat16 h[8]; uint4 u; } pk;
        #pragma unroll
        for (int e = 0; e < 8; ++e)
            pk.h[e] = __float2bfloat16(
                tanhf(Gc[(size_t)(i0 + e) * (PP * RR) + (size_t)j * RR + n]));
        *(uint4*)(dst + ((size_t)ch) * 8) = pk.u;
    }
}

// ---------------------------------------------------------------------------
// Prep: tanh + transpose G_last[i][j][l] -> tB[l][j*512 + i]  (bf16)
// ---------------------------------------------------------------------------
__global__ __launch_bounds__(256) void tanh_transpose_last(
        const float* __restrict__ G, __hip_bfloat16* __restrict__ tB) {
    __shared__ float t[32][33];
    const int j  = blockIdx.z;
    const int i0 = blockIdx.x * 32, l0 = blockIdx.y * 32;
    #pragma unroll
    for (int q = 0; q < 4; ++q) {
        int i = i0 + threadIdx.y + q * 8;
        int l = l0 + threadIdx.x;
        t[threadIdx.y + q * 8][threadIdx.x] = G[(size_t)i * (PP * OUTD) + (size_t)j * OUTD + l];
    }
    __syncthreads();
    #pragma unroll
    for (int q = 0; q < 4; ++q) {
        int l = l0 + threadIdx.y + q * 8;
        int i = i0 + threadIdx.x;
        tB[(size_t)l * KK + (size_t)j * RR + i] =
            __float2bfloat16(tanhf(t[threadIdx.x][threadIdx.y + q * 8]));
    }
}

// ---------------------------------------------------------------------------
// First core: res0[b,r] = sum_j tanh(G0[j,r]) * z[b,0]^j  -> bf16
// ---------------------------------------------------------------------------
__global__ __launch_bounds__(512) void tt_first(
        const float* __restrict__ z, const float* __restrict__ G0,
        __hip_bfloat16* __restrict__ res0) {
    __shared__ float sg[PP * RR];
    const int b = blockIdx.x;
    for (int x = threadIdx.x; x < PP * RR; x += 512) sg[x] = tanhf(G0[x]);
    __syncthreads();
    const float z0 = z[(size_t)b * DD + 0];
    const int r = threadIdx.x;
    float p = 1.0f, acc = 0.0f;
    #pragma unroll
    for (int j = 0; j < PP; ++j) { acc += sg[j * RR + r] * p; p *= z0; }
    res0[(size_t)b * RR + r] = __float2bfloat16(acc);
}

// ---------------------------------------------------------------------------
// Mid-core Horner GEMM: A resident in registers, B fragment-direct from
// global (NO LDS, NO barriers — AITER-style MFMA<->load interleave).
//   grid 512: n_blk = bid & 3 (XCD-pinned n-column), m_blk = bid >> 2.
//   256 threads = 4 waves, wave tile 32x64. A-panel (32x512) in 128 VGPRs.
//   B fragments are contiguous 1KB blocks in tBf; per (t,ks) step each wave
//   issues 4 global_load_dwordx4 for the NEXT step (register ping-pong)
//   while MFMA-ing the current one. Co-resident blocks share the same
//   n-column -> B tiles hit L1/L2.
//   NOTE: s-loop fully unrolled so a[]/bv[] indices are compile-time
//   (dynamic index demotes arrays to scratch — round-4 lesson).
// ---------------------------------------------------------------------------
__global__ __launch_bounds__(256, 2) void tt_gemm_arf(
        const __hip_bfloat16* __restrict__ resin,   // [8192][512] bf16
        const __hip_bfloat16* __restrict__ tBf,     // fragment-packed, 5MB/core
        __hip_bfloat16* __restrict__ resout,        // [8192][512] bf16
        const float* __restrict__ z, int d) {
    const int tid  = threadIdx.x;
    const int lane = tid & 63;
    const int wave = tid >> 6;
    const int bid  = blockIdx.x;
    const int n0 = (bid & 3) * 128;
    const int m0 = (bid >> 2) * 64;
    const int wm = (wave >> 1) * 32;
    const int ntw = (n0 >> 4) + (wave & 1) * 4;   // wave's first 16-col tile
    const int r16  = lane & 15;
    const int quad = lane >> 4;

    // ---- A resident in VGPRs: a[sm*16 + s], s = t*2+ks (frag layout) ----
    bf16x8 a[32];
    #pragma unroll
    for (int sm = 0; sm < 2; ++sm)
        #pragma unroll
        for (int t2 = 0; t2 < 16; ++t2)
            a[sm * 16 + t2] = *(const bf16x8*)(
                resin + (size_t)(m0 + wm + sm * 16 + r16) * RR + t2 * 32 + quad * 8);

    // ---- per-lane Horner row scales (C/D rows: wm + sm*16 + quad*4 + r) ----
    float zr[8];
    #pragma unroll
    for (int sm = 0; sm < 2; ++sm)
        #pragma unroll
        for (int r = 0; r < 4; ++r)
            zr[sm * 4 + r] = z[(size_t)(m0 + wm + sm * 16 + quad * 4 + r) * DD + d];

    f32x4 acc[2][4];
    #pragma unroll
    for (int sm = 0; sm < 2; ++sm)
        #pragma unroll
        for (int sn = 0; sn < 4; ++sn) acc[sm][sn] = f32x4{0.f, 0.f, 0.f, 0.f};

    // per-lane fragment base: block (j*16+kc)*32 + nt, 512 elems per block
    const __hip_bfloat16* pB = tBf + (size_t)ntw * 512 + (size_t)lane * 8;
    constexpr size_t KCS = 32 * 512;        // elems per kc step (16KB)
    constexpr size_t JS  = 16 * KCS;        // elems per j panel (512KB)

    bf16x8 bv[2][4];
    #pragma unroll
    for (int sn = 0; sn < 4; ++sn)
        bv[0][sn] = *(const bf16x8*)(pB + (size_t)9 * JS + sn * 512);

    #pragma unroll 1
    for (int p = 0; p < 10; ++p) {
        const int j = 9 - p;
        if (p) {
            #pragma unroll
            for (int sm = 0; sm < 2; ++sm)
                #pragma unroll
                for (int sn = 0; sn < 4; ++sn)
                    #pragma unroll
                    for (int r = 0; r < 4; ++r)
                        acc[sm][sn][r] *= zr[sm * 4 + r];
        }
        const size_t jb = (size_t)j * JS;
        #pragma unroll
        for (int s = 0; s < 16; ++s) {
            const int cur = s & 1, nxt = cur ^ 1;
            if (s < 15) {
                #pragma unroll
                for (int sn = 0; sn < 4; ++sn)
                    bv[nxt][sn] = *(const bf16x8*)(pB + jb + (size_t)(s + 1) * KCS + sn * 512);
            } else if (p < 9) {
                #pragma unroll
                for (int sn = 0; sn < 4; ++sn)
                    bv[nxt][sn] = *(const bf16x8*)(pB + jb - JS + sn * 512);
            }
            #pragma unroll
            for (int sm = 0; sm < 2; ++sm)
                #pragma unroll
                for (int sn = 0; sn < 4; ++sn)
                    acc[sm][sn] = __builtin_amdgcn_mfma_f32_16x16x32_bf16(
                        a[sm * 16 + s], bv[cur][sn], acc[sm][sn], 0, 0, 0);
        }
    }

    // ---- epilogue: bf16 store, C/D layout col=lane&15, row=quad*4+reg ----
    #pragma unroll
    for (int sm = 0; sm < 2; ++sm)
        #pragma unroll
        for (int sn = 0; sn < 4; ++sn)
            #pragma unroll
            for (int r = 0; r < 4; ++r)
                resout[(size_t)(m0 + wm + sm * 16 + quad * 4 + r) * RR
                       + n0 + (wave & 1) * 64 + sn * 16 + r16] = __float2bfloat16(acc[sm][sn][r]);
}

// ---------------------------------------------------------------------------
// Last core (N=64): j-split GEMM, partial per j, epilogue scales by zb^j.
// grid (10, 64): x = j, BN=64, single panel. (Round-2 verified structure.)
// ---------------------------------------------------------------------------
template <int BN, int NPAN, bool LAST>
__global__ __launch_bounds__(256, 2) void tt_gemm_h(
        const __hip_bfloat16* __restrict__ resin,
        const __hip_bfloat16* __restrict__ tB,
        float* __restrict__ outp,
        const float* __restrict__ z, int d) {
    constexpr int BM = 128, BK = 64;
    constexpr int SN = BN / 32;
    constexpr int BCPW = (BN / 8) / 4;

    __shared__ __hip_bfloat16 sA[BM * BK];
    __shared__ __hip_bfloat16 sB[BN * BK];

    const int tid  = threadIdx.x;
    const int lane = tid & 63;
    const int wave = tid >> 6;
    const int m0 = blockIdx.y * BM;

    int n0, jtop, jbot;
    if (LAST) {
        n0 = 0; jtop = jbot = blockIdx.x;
        outp += (size_t)blockIdx.x * ((size_t)BB * OUTD);
    } else {
        n0 = (blockIdx.x >> 1) * BN;
        const int s = blockIdx.x & 1;
        jtop = 8 + s; jbot = s;
        outp += (size_t)s * ((size_t)BB * RR);
    }

    const int wm = (wave >> 1) * 64;
    const int wn = (wave & 1) * (BN / 2);
    const int rq = (lane >> 4) * 4;

    const int asrow = lane >> 3;
    const int acswz = ((lane & 7) ^ asrow) * 8;

    f32x4 acc[4][SN];
    #pragma unroll
    for (int a = 0; a < 4; ++a)
        #pragma unroll
        for (int b = 0; b < SN; ++b) acc[a][b] = f32x4{0.f, 0.f, 0.f, 0.f};

    #pragma unroll 1
    for (int pan = 0; pan < NPAN; ++pan) {
        const int j = jtop - 2 * pan;
        const size_t kb0 = (size_t)j * RR;

        #pragma unroll 1
        for (int kt = 0; kt < 8; ++kt) {
            const int kc = kt * 64;
            #pragma unroll
            for (int q = 0; q < 4; ++q) {
                const int ch = wave * 4 + q;
                gload_lds16(resin + (size_t)(m0 + ch * 8 + asrow) * RR + kc + acswz,
                            sA + ch * 512 + lane * 8);
            }
            #pragma unroll
            for (int q = 0; q < BCPW; ++q) {
                const int ch = wave * BCPW + q;
                gload_lds16(tB + (size_t)(n0 + ch * 8 + asrow) * KK + kb0 + kc + acswz,
                            sB + ch * 512 + lane * 8);
            }
            __syncthreads();

            #pragma unroll
            for (int ks = 0; ks < 2; ++ks) {
                const int q4 = ks * 4 + (lane >> 4);
                bf16x8 av[4], bv[SN];
                #pragma unroll
                for (int s = 0; s < 4; ++s) {
                    const int row = wm + s * 16 + (lane & 15);
                    av[s] = *(const bf16x8*)(sA + row * 64 + ((q4 ^ (row & 7)) << 3));
                }
                #pragma unroll
                for (int s = 0; s < SN; ++s) {
                    const int row = wn + s * 16 + (lane & 15);
                    bv[s] = *(const bf16x8*)(sB + row * 64 + ((q4 ^ (row & 7)) << 3));
                }
                #pragma unroll
                for (int sm = 0; sm < 4; ++sm)
                    #pragma unroll
                    for (int sn = 0; sn < SN; ++sn)
                        acc[sm][sn] = __builtin_amdgcn_mfma_f32_16x16x32_bf16(
                            av[sm], bv[sn], acc[sm][sn], 0, 0, 0);
            }
            __syncthreads();
        }
    }

    const int col = lane & 15;
    #pragma unroll
    for (int sm = 0; sm < 4; ++sm) {
        float zsc[4];
        #pragma unroll
        for (int r = 0; r < 4; ++r) {
            const int row = m0 + wm + sm * 16 + rq + r;
            const float zb = z[(size_t)row * DD + d];
            float p = 1.0f;
            for (int t = 0; t < jbot; ++t) p *= zb;
            zsc[r] = p;
        }
        #pragma unroll
        for (int sn = 0; sn < SN; ++sn)
            #pragma unroll
            for (int r = 0; r < 4; ++r) {
                const int grow = m0 + wm + sm * 16 + rq + r;
                const int gcol = n0 + wn + sn * 16 + col;
                outp[(size_t)grow * (LAST ? OUTD : RR) + gcol] = acc[sm][sn][r] * zsc[r];
            }
    }
}

// ---------------------------------------------------------------------------
// out[b,l] = sum_{s<10} parts[s][b][l]
// ---------------------------------------------------------------------------
__global__ __launch_bounds__(256) void reduce10(
        const float* __restrict__ p, float* __restrict__ o) {
    const size_t i = ((size_t)blockIdx.x * 256 + threadIdx.x) * 4;
    f32x4 s = f32x4{0.f, 0.f, 0.f, 0.f};
    #pragma unroll
    for (int q = 0; q < 10; ++q)
        s += *(const f32x4*)(p + (size_t)q * (BB * OUTD) + i);
    *(f32x4*)(o + i) = s;
}

// ---------------------------------------------------------------------------
extern "C" void kernel_launch(void* const* d_in, const int* in_sizes, int n_in,
                              void* d_out, int out_size, void* d_ws, size_t ws_size,
                              hipStream_t stream) {
    const float* z     = (const float*)d_in[0];
    const float* G0    = (const float*)d_in[1];
    const float* Gmid  = (const float*)d_in[2];
    const float* Glast = (const float*)d_in[3];
    float* out = (float*)d_out;

    char* ws = (char*)d_ws;
    __hip_bfloat16* resX = (__hip_bfloat16*)ws;                          // 8 MB
    __hip_bfloat16* resY = (__hip_bfloat16*)(ws + ((size_t)8 << 20));    // 8 MB
    float* LP            = (float*)(ws + ((size_t)16 << 20));            // 20 MB (last partials)
    __hip_bfloat16* tBf    = (__hip_bfloat16*)(ws + ((size_t)48 << 20)); // 30 MB frag-packed
    __hip_bfloat16* tBlast = (__hip_bfloat16*)(ws + ((size_t)80 << 20)); // 0.64 MB

    frag_pack_mid <<<dim3(16, 10, 6), 256, 0, stream>>>(Gmid, tBf);
    tanh_transpose_last<<<dim3(16, 2, 10), dim3(32, 8), 0, stream>>>(Glast, tBlast);
    tt_first<<<BB, 512, 0, stream>>>(z, G0, resX);

    __hip_bfloat16* rin = resX;
    __hip_bfloat16* rnext = resY;
    for (int c = 0; c < 6; ++c) {
        tt_gemm_arf<<<dim3(512), 256, 0, stream>>>(
            rin, tBf + (size_t)c * RR * KK, rnext, z, c + 1);
        __hip_bfloat16* t = rin; rin = rnext; rnext = t;
    }
    tt_gemm_h<64, 1, true><<<dim3(10, BB / 128), 256, 0, stream>>>(
        rin, tBlast, LP, z, 7);
    reduce10<<<dim3((BB * OUTD) / 1024), 256, 0, stream>>>(LP, out);
}

// Round 7
// 408.055 us; speedup vs baseline: 1.2706x; 1.2706x over previous
//
#include <hip/hip_runtime.h>
#include <hip/hip_bf16.h>
#include <stdint.h>

// Problem constants
#define BB   8192   // batch
#define DD   8      // features
#define PP   10     // poly basis width
#define RR   512    // TT rank
#define OUTD 64     // output dim
#define KK   5120   // expanded K = PP*RR

typedef __bf16 bf16x8 __attribute__((ext_vector_type(8)));
typedef float  f32x4  __attribute__((ext_vector_type(4)));

// ---------------------------------------------------------------------------
// frag_pack<N>: tanh + pack G(i,j,n) = G[i*ldi + j*N + n] into MFMA
// B-fragment-linear layout: dst[(j*16+kc)*32N + nt*512 + lane*8 + e]
//   n = nt*16 + (lane&15), i = kc*32 + (lane>>4)*8 + e
// Coalesced f32x4 reads -> LDS bf16 tile (padded) -> 16B packed writes.
// grid (16, 10, C), 256 threads.
// ---------------------------------------------------------------------------
template <int N>
__global__ __launch_bounds__(256) void frag_pack(
        const float* __restrict__ G, __hip_bfloat16* __restrict__ dst, int ldi) {
    constexpr int LOGN = (N == 512) ? 9 : 6;
    __shared__ __hip_bfloat16 sT[32 * (N + 8)];
    const int kc = blockIdx.x, j = blockIdx.y, c = blockIdx.z;
    const float* Gp = G + (size_t)c * 512 * ldi;
    __hip_bfloat16* db = dst + (size_t)c * 5120 * N + (size_t)(j * 16 + kc) * 32 * N;
    #pragma unroll
    for (int e = 0; e < N / 32; ++e) {
        const int idx = (e * 256 + threadIdx.x) * 4;
        const int row = idx >> LOGN, col = idx & (N - 1);
        f32x4 v = *(const f32x4*)(Gp + (size_t)(kc * 32 + row) * ldi + (size_t)j * N + col);
        __hip_bfloat16* sp = sT + row * (N + 8) + col;
        sp[0] = __float2bfloat16(tanhf(v.x));
        sp[1] = __float2bfloat16(tanhf(v.y));
        sp[2] = __float2bfloat16(tanhf(v.z));
        sp[3] = __float2bfloat16(tanhf(v.w));
    }
    __syncthreads();
    #pragma unroll
    for (int cc = 0; cc < N / 64; ++cc) {
        const int ch = cc * 256 + threadIdx.x;
        const int nt = ch >> 6, l = ch & 63;
        const int r0 = (l >> 4) * 8, cb = nt * 16 + (l & 15);
        union { __hip_bfloat16 h[8]; uint4 u; } pk;
        #pragma unroll
        for (int e = 0; e < 8; ++e) pk.h[e] = sT[(r0 + e) * (N + 8) + cb];
        *(uint4*)(db + (size_t)ch * 8) = pk.u;
    }
}

// ---------------------------------------------------------------------------
// First core: res0[b,r] = sum_j tanh(G0[j,r]) * z[b,0]^j  -> bf16
// ---------------------------------------------------------------------------
__global__ __launch_bounds__(512) void tt_first(
        const float* __restrict__ z, const float* __restrict__ G0,
        __hip_bfloat16* __restrict__ res0) {
    __shared__ float sg[PP * RR];
    const int b = blockIdx.x;
    for (int x = threadIdx.x; x < PP * RR; x += 512) sg[x] = tanhf(G0[x]);
    __syncthreads();
    const float z0 = z[(size_t)b * DD + 0];
    const int r = threadIdx.x;
    float p = 1.0f, acc = 0.0f;
    #pragma unroll
    for (int j = 0; j < PP; ++j) { acc += sg[j * RR + r] * p; p *= z0; }
    res0[(size_t)b * RR + r] = __float2bfloat16(acc);
}

// ---------------------------------------------------------------------------
// Horner GEMM, K split ACROSS WAVES (no main-loop barriers, no B duplication
// within a block).
//   Block tile 64 x 64, 256 threads = 4 waves; wave w covers the FULL 64x64
//   output for K-slice [w*128, w*128+128) of each j-panel. A (64x128) lives
//   in 64 VGPRs per wave, loaded once. B fragments loaded direct global->VGPR
//   (1KB contiguous, depth-1 register ping-pong). Horner over j=9..0 commutes
//   with the K-split: each wave scales its partial acc by the same zr.
//   Epilogue: 3-barrier LDS tree-sum of the 4 partials, coalesced store.
//   grid (m=128, n): consecutive blockIdx.x share the n-column -> L1/L2 reuse.
//   NOTE: all fragment arrays indexed by compile-time constants only
//   (dynamic index demotes to scratch — round-4 lesson).
// ---------------------------------------------------------------------------
template <bool LASTV, int NTOT>
__global__ __launch_bounds__(256, 2) void tt_gemm_ks(
        const __hip_bfloat16* __restrict__ resin,   // [8192][512] bf16
        const __hip_bfloat16* __restrict__ tBf,     // fragment-packed
        void* __restrict__ outp,
        const float* __restrict__ z, int d) {
    __shared__ f32x4 red[2][16][64];   // 32 KB: two 16KB partial-sum regions

    const int tid  = threadIdx.x;
    const int lane = tid & 63;
    const int wave = tid >> 6;
    const int m0 = blockIdx.x * 64;
    const int nb = blockIdx.y;
    const int r16 = lane & 15, quad = lane >> 4;

    // ---- A resident: a[msub*4 + kst], rows m0+msub*16+r16, k = wave*128+kst*32+quad*8
    bf16x8 a[16];
    #pragma unroll
    for (int ms = 0; ms < 4; ++ms)
        #pragma unroll
        for (int kst = 0; kst < 4; ++kst)
            a[ms * 4 + kst] = *(const bf16x8*)(
                resin + (size_t)(m0 + ms * 16 + r16) * RR + wave * 128 + kst * 32 + quad * 8);

    // ---- Horner row scales (C/D rows: ms*16 + quad*4 + r) ----
    float zr[16];
    #pragma unroll
    for (int ms = 0; ms < 4; ++ms)
        #pragma unroll
        for (int r = 0; r < 4; ++r)
            zr[ms * 4 + r] = z[(size_t)(m0 + ms * 16 + quad * 4 + r) * DD + d];

    f32x4 acc[4][4];
    #pragma unroll
    for (int ms = 0; ms < 4; ++ms)
        #pragma unroll
        for (int sn = 0; sn < 4; ++sn) acc[ms][sn] = f32x4{0.f, 0.f, 0.f, 0.f};

    constexpr size_t SK = (size_t)NTOT * 512;   // elems per kc step
    constexpr size_t PJ = 16 * SK;              // elems per j panel
    const __hip_bfloat16* pB = tBf + (size_t)nb * 4 * 512
                             + (size_t)wave * 4 * SK + (size_t)lane * 8;

    bf16x8 bv[2][4];
    #pragma unroll
    for (int sn = 0; sn < 4; ++sn)
        bv[0][sn] = *(const bf16x8*)(pB + (size_t)9 * PJ + sn * 512);

    #pragma unroll 1
    for (int p = 0; p < 10; ++p) {
        const int j = 9 - p;
        if (p) {
            #pragma unroll
            for (int ms = 0; ms < 4; ++ms)
                #pragma unroll
                for (int sn = 0; sn < 4; ++sn)
                    #pragma unroll
                    for (int r = 0; r < 4; ++r)
                        acc[ms][sn][r] *= zr[ms * 4 + r];
        }
        const size_t jb = (size_t)j * PJ;
        #pragma unroll
        for (int s = 0; s < 4; ++s) {
            const int cur = s & 1, nxt = cur ^ 1;
            if (s < 3) {
                #pragma unroll
                for (int sn = 0; sn < 4; ++sn)
                    bv[nxt][sn] = *(const bf16x8*)(pB + jb + (size_t)(s + 1) * SK + sn * 512);
            } else if (p < 9) {
                #pragma unroll
                for (int sn = 0; sn < 4; ++sn)
                    bv[nxt][sn] = *(const bf16x8*)(pB + jb - PJ + sn * 512);
            }
            #pragma unroll
            for (int ms = 0; ms < 4; ++ms)
                #pragma unroll
                for (int sn = 0; sn < 4; ++sn)
                    acc[ms][sn] = __builtin_amdgcn_mfma_f32_16x16x32_bf16(
                        a[ms * 4 + s], bv[cur][sn], acc[ms][sn], 0, 0, 0);
        }
    }

    // ---- cross-wave K reduction: waves 1,3 stash; 0,2 add; 2 stash; 0 adds
    if (wave & 1) {
        const int idx = wave >> 1;
        #pragma unroll
        for (int i = 0; i < 16; ++i) red[idx][i][lane] = acc[i >> 2][i & 3];
    }
    __syncthreads();
    if (wave == 0) {
        #pragma unroll
        for (int i = 0; i < 16; ++i) acc[i >> 2][i & 3] += red[0][i][lane];
    }
    if (wave == 2) {
        #pragma unroll
        for (int i = 0; i < 16; ++i) {
            f32x4 t = acc[i >> 2][i & 3] + red[1][i][lane];
            red[1][i][lane] = t;
        }
    }
    __syncthreads();
    float* rc = (float*)&red[0][0][0];   // reuse region0 as [64][64] row-major
    if (wave == 0) {
        #pragma unroll
        for (int i = 0; i < 16; ++i) acc[i >> 2][i & 3] += red[1][i][lane];
        #pragma unroll
        for (int ms = 0; ms < 4; ++ms)
            #pragma unroll
            for (int sn = 0; sn < 4; ++sn)
                #pragma unroll
                for (int r = 0; r < 4; ++r)
                    rc[(ms * 16 + quad * 4 + r) * 64 + sn * 16 + r16] = acc[ms][sn][r];
    }
    __syncthreads();

    // ---- coalesced store: thread -> (row = tid>>2, 16 cols) ----
    const int row = tid >> 2, cg = (tid & 3) * 16;
    if (LASTV) {
        float* o = (float*)outp;
        #pragma unroll
        for (int q = 0; q < 4; ++q)
            *(f32x4*)(o + (size_t)(m0 + row) * OUTD + cg + q * 4) =
                *(const f32x4*)(rc + row * 64 + cg + q * 4);
    } else {
        __hip_bfloat16* o = (__hip_bfloat16*)outp;
        #pragma unroll
        for (int h = 0; h < 2; ++h) {
            union { __hip_bfloat16 hh[8]; uint4 u; } pk;
            #pragma unroll
            for (int e = 0; e < 8; ++e)
                pk.hh[e] = __float2bfloat16(rc[row * 64 + cg + h * 8 + e]);
            *(uint4*)(o + (size_t)(m0 + row) * RR + nb * 64 + cg + h * 8) = pk.u;
        }
    }
}

// ---------------------------------------------------------------------------
extern "C" void kernel_launch(void* const* d_in, const int* in_sizes, int n_in,
                              void* d_out, int out_size, void* d_ws, size_t ws_size,
                              hipStream_t stream) {
    const float* z     = (const float*)d_in[0];
    const float* G0    = (const float*)d_in[1];
    const float* Gmid  = (const float*)d_in[2];
    const float* Glast = (const float*)d_in[3];
    float* out = (float*)d_out;

    char* ws = (char*)d_ws;
    __hip_bfloat16* resX   = (__hip_bfloat16*)ws;                        // 8 MB
    __hip_bfloat16* resY   = (__hip_bfloat16*)(ws + ((size_t)8 << 20));  // 8 MB
    __hip_bfloat16* tBf    = (__hip_bfloat16*)(ws + ((size_t)16 << 20)); // 30 MB frag-packed mid
    __hip_bfloat16* tBlf   = (__hip_bfloat16*)(ws + ((size_t)48 << 20)); // 640 KB frag-packed last

    frag_pack<512><<<dim3(16, 10, 6), 256, 0, stream>>>(Gmid,  tBf,  PP * RR);
    frag_pack<64> <<<dim3(16, 10, 1), 256, 0, stream>>>(Glast, tBlf, PP * OUTD);
    tt_first<<<BB, 512, 0, stream>>>(z, G0, resX);

    __hip_bfloat16* rin = resX;
    __hip_bfloat16* rnext = resY;
    for (int c = 0; c < 6; ++c) {
        tt_gemm_ks<false, 32><<<dim3(BB / 64, RR / 64), 256, 0, stream>>>(
            rin, tBf + (size_t)c * RR * KK, rnext, z, c + 1);
        __hip_bfloat16* t = rin; rin = rnext; rnext = t;
    }
    tt_gemm_ks<true, 4><<<dim3(BB / 64, 1), 256, 0, stream>>>(
        rin, tBlf, out, z, 7);
}

// Round 8
// 388.528 us; speedup vs baseline: 1.3344x; 1.0503x over previous
//
#include <hip/hip_runtime.h>
#include <hip/hip_bf16.h>
#include <stdint.h>

// Problem constants
#define BB   8192   // batch
#define DD   8      // features
#define PP   10     // poly basis width
#define RR   512    // TT rank
#define OUTD 64     // output dim
#define KK   5120   // expanded K = PP*RR

typedef __bf16 bf16x8 __attribute__((ext_vector_type(8)));
typedef float  f32x4  __attribute__((ext_vector_type(4)));

// ---------------------------------------------------------------------------
// frag_pack<N>: tanh + pack G(i,j,n) = G[i*ldi + j*N + n] into MFMA
// B-fragment-linear layout: dst[(j*16+kc)*32N + nt*512 + lane*8 + e]
//   n = nt*16 + (lane&15), i = kc*32 + (lane>>4)*8 + e
// Coalesced f32x4 reads -> LDS bf16 tile (padded) -> 16B packed writes.
// grid (16, 10, C), 256 threads.
// ---------------------------------------------------------------------------
template <int N>
__global__ __launch_bounds__(256) void frag_pack(
        const float* __restrict__ G, __hip_bfloat16* __restrict__ dst, int ldi) {
    constexpr int LOGN = (N == 512) ? 9 : 6;
    __shared__ __hip_bfloat16 sT[32 * (N + 8)];
    const int kc = blockIdx.x, j = blockIdx.y, c = blockIdx.z;
    const float* Gp = G + (size_t)c * 512 * ldi;
    __hip_bfloat16* db = dst + (size_t)c * 5120 * N + (size_t)(j * 16 + kc) * 32 * N;
    #pragma unroll
    for (int e = 0; e < N / 32; ++e) {
        const int idx = (e * 256 + threadIdx.x) * 4;
        const int row = idx >> LOGN, col = idx & (N - 1);
        f32x4 v = *(const f32x4*)(Gp + (size_t)(kc * 32 + row) * ldi + (size_t)j * N + col);
        __hip_bfloat16* sp = sT + row * (N + 8) + col;
        sp[0] = __float2bfloat16(tanhf(v.x));
        sp[1] = __float2bfloat16(tanhf(v.y));
        sp[2] = __float2bfloat16(tanhf(v.z));
        sp[3] = __float2bfloat16(tanhf(v.w));
    }
    __syncthreads();
    #pragma unroll
    for (int cc = 0; cc < N / 64; ++cc) {
        const int ch = cc * 256 + threadIdx.x;
        const int nt = ch >> 6, l = ch & 63;
        const int r0 = (l >> 4) * 8, cb = nt * 16 + (l & 15);
        union { __hip_bfloat16 h[8]; uint4 u; } pk;
        #pragma unroll
        for (int e = 0; e < 8; ++e) pk.h[e] = sT[(r0 + e) * (N + 8) + cb];
        *(uint4*)(db + (size_t)ch * 8) = pk.u;
    }
}

// ---------------------------------------------------------------------------
// tanh(G0) once: 5120 elems.
// ---------------------------------------------------------------------------
__global__ __launch_bounds__(512) void tanh_g0(
        const float* __restrict__ G0, float* __restrict__ tG0) {
    const int i = blockIdx.x * 512 + threadIdx.x;
    tG0[i] = tanhf(G0[i]);
}

// ---------------------------------------------------------------------------
// First core: res0[b,r] = Horner_j( tG0[j,r]; z[b,0] ) -> bf16
// grid 256 blocks x 512 threads; tG0 column held in 10 VGPRs, 32 batches/blk.
// ---------------------------------------------------------------------------
__global__ __launch_bounds__(512) void tt_first(
        const float* __restrict__ z, const float* __restrict__ tG0,
        __hip_bfloat16* __restrict__ res0) {
    const int r = threadIdx.x;
    const int b0 = blockIdx.x * 32;
    float tg[10];
    #pragma unroll
    for (int j = 0; j < 10; ++j) tg[j] = tG0[j * RR + r];
    #pragma unroll 1
    for (int b = 0; b < 32; ++b) {
        const float z0 = z[(size_t)(b0 + b) * DD];
        float acc = tg[9];
        #pragma unroll
        for (int j = 8; j >= 0; --j) acc = acc * z0 + tg[j];
        res0[(size_t)(b0 + b) * RR + r] = __float2bfloat16(acc);
    }
}

// ---------------------------------------------------------------------------
// Horner GEMM, K split across waves, B via DEPTH-3 register prefetch ring.
//   Block tile 64x64, 4 waves; wave w owns K-slice [w*128, w*128+128) of each
//   j-panel, A (64x128) resident in 64 VGPRs. B fragments (contiguous 1KB)
//   loaded global->VGPR into a 4-slot ring: loads for step s+3 issue before
//   the MFMAs of step s (issue-to-use gap ~3x310 cyc >= L2 latency), so one
//   wave overlaps its own loads with its own MFMA. All ring slots are
//   compile-time (dynamic index -> scratch, round-4 lesson).
//   Horner over j=9..0; epilogue: LDS tree-sum of 4 K-partials + store.
// ---------------------------------------------------------------------------
template <bool LASTV, int NTOT>
__global__ __launch_bounds__(256, 2) void tt_gemm_ks(
        const __hip_bfloat16* __restrict__ resin,   // [8192][512] bf16
        const __hip_bfloat16* __restrict__ tBf,     // fragment-packed
        void* __restrict__ outp,
        const float* __restrict__ z, int d) {
    __shared__ f32x4 red[2][16][64];   // 32 KB

    const int tid  = threadIdx.x;
    const int lane = tid & 63;
    const int wave = tid >> 6;
    const int m0 = blockIdx.x * 64;
    const int nb = blockIdx.y;
    const int r16 = lane & 15, quad = lane >> 4;

    // ---- A resident: a[ms*4 + s], rows m0+ms*16+r16, k = wave*128+s*32+quad*8
    bf16x8 a[16];
    #pragma unroll
    for (int ms = 0; ms < 4; ++ms)
        #pragma unroll
        for (int kst = 0; kst < 4; ++kst)
            a[ms * 4 + kst] = *(const bf16x8*)(
                resin + (size_t)(m0 + ms * 16 + r16) * RR + wave * 128 + kst * 32 + quad * 8);

    // ---- Horner row scales (C/D rows: ms*16 + quad*4 + r) ----
    float zr[16];
    #pragma unroll
    for (int ms = 0; ms < 4; ++ms)
        #pragma unroll
        for (int r = 0; r < 4; ++r)
            zr[ms * 4 + r] = z[(size_t)(m0 + ms * 16 + quad * 4 + r) * DD + d];

    f32x4 acc[4][4];
    #pragma unroll
    for (int ms = 0; ms < 4; ++ms)
        #pragma unroll
        for (int sn = 0; sn < 4; ++sn) acc[ms][sn] = f32x4{0.f, 0.f, 0.f, 0.f};

    constexpr size_t SK = (size_t)NTOT * 512;   // elems per kc step
    constexpr size_t PJ = 16 * SK;              // elems per j panel
    const __hip_bfloat16* pB = tBf + (size_t)nb * 4 * 512
                             + (size_t)wave * 4 * SK + (size_t)lane * 8;

    // ---- 4-slot ring; preload steps 0,1,2 of panel j=9 ----
    bf16x8 bv[4][4];
    #pragma unroll
    for (int s = 0; s < 3; ++s)
        #pragma unroll
        for (int sn = 0; sn < 4; ++sn)
            bv[s][sn] = *(const bf16x8*)(pB + (size_t)9 * PJ + (size_t)s * SK + sn * 512);

#define MFMA_STEP(SLOT)                                                        \
    _Pragma("unroll")                                                          \
    for (int ms = 0; ms < 4; ++ms)                                             \
        _Pragma("unroll")                                                      \
        for (int sn = 0; sn < 4; ++sn)                                         \
            acc[ms][sn] = __builtin_amdgcn_mfma_f32_16x16x32_bf16(             \
                a[ms * 4 + SLOT], bv[SLOT][sn], acc[ms][sn], 0, 0, 0);

    #pragma unroll 1
    for (int p = 0; p < 10; ++p) {
        const int j = 9 - p;
        if (p) {
            #pragma unroll
            for (int ms = 0; ms < 4; ++ms)
                #pragma unroll
                for (int sn = 0; sn < 4; ++sn)
                    #pragma unroll
                    for (int r = 0; r < 4; ++r)
                        acc[ms][sn][r] *= zr[ms * 4 + r];
        }
        const size_t jb = (size_t)j * PJ;
        // s=0: prefetch (p, s=3) -> slot3; compute slot0
        #pragma unroll
        for (int sn = 0; sn < 4; ++sn)
            bv[3][sn] = *(const bf16x8*)(pB + jb + (size_t)3 * SK + sn * 512);
        MFMA_STEP(0)
        // s=1: prefetch (p+1, 0) -> slot0; compute slot1
        if (p < 9) {
            #pragma unroll
            for (int sn = 0; sn < 4; ++sn)
                bv[0][sn] = *(const bf16x8*)(pB + jb - PJ + sn * 512);
        }
        MFMA_STEP(1)
        // s=2: prefetch (p+1, 1) -> slot1; compute slot2
        if (p < 9) {
            #pragma unroll
            for (int sn = 0; sn < 4; ++sn)
                bv[1][sn] = *(const bf16x8*)(pB + jb - PJ + SK + sn * 512);
        }
        MFMA_STEP(2)
        // s=3: prefetch (p+1, 2) -> slot2; compute slot3
        if (p < 9) {
            #pragma unroll
            for (int sn = 0; sn < 4; ++sn)
                bv[2][sn] = *(const bf16x8*)(pB + jb - PJ + 2 * SK + sn * 512);
        }
        MFMA_STEP(3)
    }
#undef MFMA_STEP

    // ---- cross-wave K reduction ----
    if (wave & 1) {
        const int idx = wave >> 1;
        #pragma unroll
        for (int i = 0; i < 16; ++i) red[idx][i][lane] = acc[i >> 2][i & 3];
    }
    __syncthreads();
    if (wave == 0) {
        #pragma unroll
        for (int i = 0; i < 16; ++i) acc[i >> 2][i & 3] += red[0][i][lane];
    }
    if (wave == 2) {
        #pragma unroll
        for (int i = 0; i < 16; ++i) {
            f32x4 t = acc[i >> 2][i & 3] + red[1][i][lane];
            red[1][i][lane] = t;
        }
    }
    __syncthreads();
    float* rc = (float*)&red[0][0][0];   // region0 as [64][64] row-major
    if (wave == 0) {
        #pragma unroll
        for (int i = 0; i < 16; ++i) acc[i >> 2][i & 3] += red[1][i][lane];
        #pragma unroll
        for (int ms = 0; ms < 4; ++ms)
            #pragma unroll
            for (int sn = 0; sn < 4; ++sn)
                #pragma unroll
                for (int r = 0; r < 4; ++r)
                    rc[(ms * 16 + quad * 4 + r) * 64 + sn * 16 + r16] = acc[ms][sn][r];
    }
    __syncthreads();

    // ---- coalesced store: thread -> (row = tid>>2, 16 cols) ----
    const int row = tid >> 2, cg = (tid & 3) * 16;
    if (LASTV) {
        float* o = (float*)outp;
        #pragma unroll
        for (int q = 0; q < 4; ++q)
            *(f32x4*)(o + (size_t)(m0 + row) * OUTD + cg + q * 4) =
                *(const f32x4*)(rc + row * 64 + cg + q * 4);
    } else {
        __hip_bfloat16* o = (__hip_bfloat16*)outp;
        #pragma unroll
        for (int h = 0; h < 2; ++h) {
            union { __hip_bfloat16 hh[8]; uint4 u; } pk;
            #pragma unroll
            for (int e = 0; e < 8; ++e)
                pk.hh[e] = __float2bfloat16(rc[row * 64 + cg + h * 8 + e]);
            *(uint4*)(o + (size_t)(m0 + row) * RR + nb * 64 + cg + h * 8) = pk.u;
        }
    }
}

// ---------------------------------------------------------------------------
extern "C" void kernel_launch(void* const* d_in, const int* in_sizes, int n_in,
                              void* d_out, int out_size, void* d_ws, size_t ws_size,
                              hipStream_t stream) {
    const float* z     = (const float*)d_in[0];
    const float* G0    = (const float*)d_in[1];
    const float* Gmid  = (const float*)d_in[2];
    const float* Glast = (const float*)d_in[3];
    float* out = (float*)d_out;

    char* ws = (char*)d_ws;
    __hip_bfloat16* resX   = (__hip_bfloat16*)ws;                        // 8 MB
    __hip_bfloat16* resY   = (__hip_bfloat16*)(ws + ((size_t)8 << 20));  // 8 MB
    __hip_bfloat16* tBf    = (__hip_bfloat16*)(ws + ((size_t)16 << 20)); // 30 MB frag-packed mid
    __hip_bfloat16* tBlf   = (__hip_bfloat16*)(ws + ((size_t)48 << 20)); // 640 KB frag-packed last
    float* tG0             = (float*)(ws + ((size_t)52 << 20));          // 20 KB tanh(G0)

    frag_pack<512><<<dim3(16, 10, 6), 256, 0, stream>>>(Gmid,  tBf,  PP * RR);
    frag_pack<64> <<<dim3(16, 10, 1), 256, 0, stream>>>(Glast, tBlf, PP * OUTD);
    tanh_g0<<<dim3(10), 512, 0, stream>>>(G0, tG0);
    tt_first<<<dim3(BB / 32), 512, 0, stream>>>(z, tG0, resX);

    __hip_bfloat16* rin = resX;
    __hip_bfloat16* rnext = resY;
    for (int c = 0; c < 6; ++c) {
        tt_gemm_ks<false, 32><<<dim3(BB / 64, RR / 64), 256, 0, stream>>>(
            rin, tBf + (size_t)c * RR * KK, rnext, z, c + 1);
        __hip_bfloat16* t = rin; rin = rnext; rnext = t;
    }
    tt_gemm_ks<true, 4><<<dim3(BB / 64, 1), 256, 0, stream>>>(
        rin, tBlf, out, z, 7);
}